// Round 1
// 511.197 us; speedup vs baseline: 1.0762x; 1.0762x over previous
//
#include <hip/hip_runtime.h>
#include <hip/hip_bf16.h>

#define H 512
#define W 512
#define C 32
#define O 32
#define TW 64
#define TH 4

using bf16x8 = __attribute__((ext_vector_type(8))) short;
using f32x4  = __attribute__((ext_vector_type(4))) float;

__device__ __forceinline__ unsigned short f2bf(float f) {
    union { float f; unsigned u; } c; c.f = f;
    unsigned r = c.u + 0x7fffu + ((c.u >> 16) & 1u);
    return (unsigned short)(r >> 16);
}

// Reconstruct w[o, ci, 3, 3] from CP factors, store bf16 as w[s][o][ci]
// (ci contiguous => B-fragment loads are single 16B reads).
// o = i*16 + j*4 + k (in-dims of k0/k1/k2), ci = a*16 + b*4 + c (out-dims),
// matching the reference's 'gijkabchw' -> (32, 32, 3, 3) reshape.
__global__ void recon_w(const float* __restrict__ k0, const float* __restrict__ k1,
                        const float* __restrict__ k2, const float* __restrict__ k3,
                        unsigned short* __restrict__ wout) {
    int idx = blockIdx.x * 256 + threadIdx.x;
    if (idx >= 9 * 32 * 32) return;
    int ci = idx & 31;
    int o  = (idx >> 5) & 31;
    int s  = idx >> 10;                 // 0..8 = dh*3+dw
    int i = o >> 4, j = (o >> 2) & 3, k = o & 3;
    int a = ci >> 4, b = (ci >> 2) & 3, c = ci & 3;
    float acc = 0.f;
    #pragma unroll
    for (int r = 0; r < 8; ++r)
        acc += k0[(i*2 + a)*8 + r] * k1[(j*4 + b)*8 + r]
             * k2[(k*4 + c)*8 + r] * k3[s*8 + r];
    wout[idx] = f2bf(acc);
}

// Implicit-GEMM conv: per block, a TW x TH pixel tile for all 32 out chans.
// MFMA 16x16x32 bf16: M=16 pixels (x-consecutive), N=16 o, K=32 ci; 9 taps.
// TH=4 => 25.3 KB LDS => 6 blocks/CU (was 3 at TH=8): latency hiding via TLP.
// LDS ci-quad slot is XOR-swizzled by x-pixel (involution, applied on both
// write and read) so ds_write_b128/ds_read_b128 are bank-uniform.
__launch_bounds__(256, 4)
__global__ void conv_mfma(const float* __restrict__ x,
                          const unsigned short* __restrict__ wq,
                          const float* __restrict__ bias,
                          float* __restrict__ out) {
    // [row][gx][ci-slot], ci contiguous per 8 => A-frag = one ds_read_b128
    __shared__ __align__(16) unsigned short sx[TH + 2][TW + 2][C];

    const int tid = threadIdx.x;
    const int bid = blockIdx.x;
    const int n  = bid >> 10;           // 1024 tiles per image (128 ty x 8 tx)
    const int r2 = bid & 1023;
    const int ty = r2 >> 3;             // 0..127
    const int tx = r2 & 7;              // 0..7
    const int y0 = ty * TH, x0 = tx * TW;

    const int lane = tid & 63;
    const int pix  = lane & 15;
    const int quad = lane >> 4;

    // B fragments in registers: B[k=ci=quad*8+j][n=o=h*16+pix]
    bf16x8 bw[9][2];
    #pragma unroll
    for (int s = 0; s < 9; ++s)
        #pragma unroll
        for (int h = 0; h < 2; ++h)
            bw[s][h] = *(const bf16x8*)(wq + ((s*32 + h*16 + pix)*32 + quad*8));

    // Stage x tile -> LDS bf16. Task = (row, ciq, gx); consecutive tid =>
    // consecutive gx with fixed (ci,row) => coalesced global dword loads.
    // Each task gathers 8 ci values for one pixel, packs one 16B LDS write
    // into the XOR-swizzled ci-quad slot (bank-uniform across the wave).
    for (int task = tid; task < (TH + 2) * 4 * (TW + 2); task += 256) {
        int gxl = task % (TW + 2);
        int t2  = task / (TW + 2);
        int ciq = t2 & 3;
        int row = t2 >> 2;
        int gy = y0 + row - 1;
        int gx = x0 + gxl - 1;
        bool inb = (gy >= 0) && (gy < H) && (gx >= 0) && (gx < W);
        const float* p = x + (((n*C + ciq*8)*H + gy)*W + gx);
        float v[8];
        #pragma unroll
        for (int j2 = 0; j2 < 8; ++j2) v[j2] = inb ? p[j2 * H * W] : 0.f;
        uint4 pk;
        pk.x = (unsigned)f2bf(v[0]) | ((unsigned)f2bf(v[1]) << 16);
        pk.y = (unsigned)f2bf(v[2]) | ((unsigned)f2bf(v[3]) << 16);
        pk.z = (unsigned)f2bf(v[4]) | ((unsigned)f2bf(v[5]) << 16);
        pk.w = (unsigned)f2bf(v[6]) | ((unsigned)f2bf(v[7]) << 16);
        int pos = ciq ^ ((gxl >> 1) & 3);           // bank swizzle (involution)
        *(uint4*)&sx[row][gxl][pos * 8] = pk;
    }
    __syncthreads();

    const int wave = tid >> 6;          // each wave owns 1 row of the 4-row tile
    const float b0 = bias[pix];
    const float b1 = bias[16 + pix];
    const int wrow = wave;

    #pragma unroll
    for (int mt = 0; mt < 4; ++mt) {
        const int xm = mt << 4;
        f32x4 acc0 = {0.f, 0.f, 0.f, 0.f};
        f32x4 acc1 = {0.f, 0.f, 0.f, 0.f};
        #pragma unroll
        for (int s = 0; s < 9; ++s) {
            const int dy = s / 3, dx = s % 3;  // const-folded (unrolled)
            // A[m=pix][k=ci]: x at (y0+wrow+dy-1, x0+xm+pix+dx-1)
            const int xp = xm + pix + dx;
            const int pos = quad ^ ((xp >> 1) & 3);  // same involution as write
            bf16x8 a = *(const bf16x8*)&sx[wrow + dy][xp][pos * 8];
            acc0 = __builtin_amdgcn_mfma_f32_16x16x32_bf16(a, bw[s][0], acc0, 0, 0, 0);
            acc1 = __builtin_amdgcn_mfma_f32_16x16x32_bf16(a, bw[s][1], acc1, 0, 0, 0);
        }
        // D: m = quad*4 + reg (pixel), n = pix (o)
        const int gy = y0 + wrow;
        const int base0 = ((n*O + pix)      * H + gy) * W + x0 + xm + quad * 4;
        const int base1 = ((n*O + 16 + pix) * H + gy) * W + x0 + xm + quad * 4;
        f32x4 v0 = acc0 + b0;
        f32x4 v1 = acc1 + b1;
        *(f32x4*)(out + base0) = v0;    // 16B-aligned: quad*4 floats
        *(f32x4*)(out + base1) = v1;
    }
}

extern "C" void kernel_launch(void* const* d_in, const int* in_sizes, int n_in,
                              void* d_out, int out_size, void* d_ws, size_t ws_size,
                              hipStream_t stream) {
    const float* x    = (const float*)d_in[0];
    const float* k0   = (const float*)d_in[1];
    const float* k1   = (const float*)d_in[2];
    const float* k2   = (const float*)d_in[3];
    const float* k3   = (const float*)d_in[4];
    const float* bias = (const float*)d_in[5];
    float* out = (float*)d_out;
    unsigned short* wbuf = (unsigned short*)d_ws;  // 9216 bf16 = 18 KB

    recon_w<<<36, 256, 0, stream>>>(k0, k1, k2, k3, wbuf);
    // 8 images * (512/TH=128) * (512/TW=8) = 8192 blocks
    conv_mfma<<<8192, 256, 0, stream>>>(x, wbuf, bias, out);
}

// Round 2
// 478.573 us; speedup vs baseline: 1.1495x; 1.0682x over previous
//
#include <hip/hip_runtime.h>
#include <hip/hip_bf16.h>

#define H 512
#define W 512
#define C 32
#define O 32
#define TW 64
#define TH 4
#define SH 16      // rows per block (4 strips of TH=4)
#define NS 4       // strips per block
#define RING 12    // LDS row ring (read window 6 + write window 4 <= 12)

using bf16x8 = __attribute__((ext_vector_type(8))) short;
using f32x4  = __attribute__((ext_vector_type(4))) float;

__device__ __forceinline__ unsigned short f2bf(float f) {
    union { float f; unsigned u; } c; c.f = f;
    unsigned r = c.u + 0x7fffu + ((c.u >> 16) & 1u);
    return (unsigned short)(r >> 16);
}

__device__ __forceinline__ uint4 pack8(const float* v) {
    uint4 pk;
    pk.x = (unsigned)f2bf(v[0]) | ((unsigned)f2bf(v[1]) << 16);
    pk.y = (unsigned)f2bf(v[2]) | ((unsigned)f2bf(v[3]) << 16);
    pk.z = (unsigned)f2bf(v[4]) | ((unsigned)f2bf(v[5]) << 16);
    pk.w = (unsigned)f2bf(v[6]) | ((unsigned)f2bf(v[7]) << 16);
    return pk;
}

// Reconstruct w[o, ci, 3, 3] from CP factors, store bf16 as w[s][o][ci]
// (ci contiguous => B-fragment loads are single 16B reads).
__global__ void recon_w(const float* __restrict__ k0, const float* __restrict__ k1,
                        const float* __restrict__ k2, const float* __restrict__ k3,
                        unsigned short* __restrict__ wout) {
    int idx = blockIdx.x * 256 + threadIdx.x;
    if (idx >= 9 * 32 * 32) return;
    int ci = idx & 31;
    int o  = (idx >> 5) & 31;
    int s  = idx >> 10;                 // 0..8 = dh*3+dw
    int i = o >> 4, j = (o >> 2) & 3, k = o & 3;
    int a = ci >> 4, b = (ci >> 2) & 3, c = ci & 3;
    float acc = 0.f;
    #pragma unroll
    for (int r = 0; r < 8; ++r)
        acc += k0[(i*2 + a)*8 + r] * k1[(j*4 + b)*8 + r]
             * k2[(k*4 + c)*8 + r] * k3[s*8 + r];
    wout[idx] = f2bf(acc);
}

// Strip-pipelined implicit-GEMM conv. Block = TW x SH pixels, all 32 o-chans.
// LDS = 12-row ring; per strip: issue next strip's global loads (held in
// regs), compute current strip (36 ds_read + 72 MFMA + stores per wave),
// then pack+ds_write the staged rows and barrier. Loads stay in flight
// under the MFMA phase => memory stream has no barrier-drain duty cycle.
__launch_bounds__(256, 3)
__global__ void conv_mfma(const float* __restrict__ x,
                          const unsigned short* __restrict__ wq,
                          const float* __restrict__ bias,
                          float* __restrict__ out) {
    // [ring-row][gx][ci-slot]; ci-quad slot XOR-swizzled by x (involution,
    // same on write and read) => ds_write_b128/ds_read_b128 bank-uniform.
    __shared__ __align__(16) unsigned short sx[RING][TW + 2][C];

    const int tid = threadIdx.x;
    const int bid = blockIdx.x;
    const int n  = bid >> 8;            // 256 tiles per image (32 ty x 8 tx)
    const int ty = (bid >> 3) & 31;
    const int tx = bid & 7;
    const int y0 = ty * SH, x0 = tx * TW;

    const int lane = tid & 63;
    const int wave = tid >> 6;          // wave owns row (wave) of each strip
    const int pix  = lane & 15;
    const int quad = lane >> 4;

    // B fragments in registers (amortized over NS strips):
    // B[k=ci=quad*8+j][n=o=h*16+pix]
    bf16x8 bw[9][2];
    #pragma unroll
    for (int s = 0; s < 9; ++s)
        #pragma unroll
        for (int h = 0; h < 2; ++h)
            bw[s][h] = *(const bf16x8*)(wq + ((s*32 + h*16 + pix)*32 + quad*8));

    // ---- prologue: stage ring rows r=0..5 (gy = y0-1+r) ----
    for (int task = tid; task < 6 * 4 * 66; task += 256) {
        int gxl = task % 66;
        int t2  = task / 66;
        int ciq = t2 & 3;
        int r   = t2 >> 2;              // 0..5 == ring slot
        int gy = y0 - 1 + r;            // < H always here
        int gx = x0 + gxl - 1;
        bool inb = (gy >= 0) && (gx >= 0) && (gx < W);
        const float* p = x + (((n*C + ciq*8)*H + gy)*W + gx);
        float v[8];
        #pragma unroll
        for (int j2 = 0; j2 < 8; ++j2) v[j2] = inb ? p[j2 * H * W] : 0.f;
        int pos = ciq ^ ((gxl >> 1) & 3);
        *(uint4*)&sx[r][gxl][pos * 8] = pack8(v);
    }
    __syncthreads();

    const float b0 = bias[pix];
    const float b1 = bias[16 + pix];

    #pragma unroll
    for (int s = 0; s < NS; ++s) {
        const int rbase = (4 * s) % RING;

        // ---- issue global loads for strip s+1 (rows r = 4s+6..4s+9) ----
        // main: wave w -> ciq=w, row k, columns gxl=lane+1 (coalesced 256B)
        float v[4][8];
        float vh[8];
        int hcol = 0, hciq = 0, hrow = 0;
        if (s + 1 < NS) {
            #pragma unroll
            for (int k = 0; k < 4; ++k) {
                int gy = y0 + 4*s + 5 + k;          // r = 4s+6+k
                bool inb = (gy < H);                // uniform per wave
                const float* p = x + (((n*C + wave*8)*H + gy)*W + x0 + lane);
                #pragma unroll
                for (int j2 = 0; j2 < 8; ++j2)
                    v[k][j2] = inb ? p[j2 * H * W] : 0.f;
            }
            // halo columns gxl in {0,65}: 32 tasks on threads 0..31
            if (tid < 32) {
                hcol = (tid & 1) ? 65 : 0;
                hciq = (tid >> 1) & 3;
                hrow = tid >> 3;
                int gy = y0 + 4*s + 5 + hrow;
                int gx = x0 + hcol - 1;
                bool inb = (gy < H) && (gx >= 0) && (gx < W);
                const float* p = x + (((n*C + hciq*8)*H + gy)*W + gx);
                #pragma unroll
                for (int j2 = 0; j2 < 8; ++j2)
                    vh[j2] = inb ? p[j2 * H * W] : 0.f;
            }
        }

        // ---- compute strip s (reads ring rows r = 4s .. 4s+5) ----
        const int gy_out = y0 + 4*s + wave;
        #pragma unroll
        for (int mt = 0; mt < 4; ++mt) {
            const int xm = mt << 4;
            f32x4 acc0 = {0.f, 0.f, 0.f, 0.f};
            f32x4 acc1 = {0.f, 0.f, 0.f, 0.f};
            #pragma unroll
            for (int stp = 0; stp < 9; ++stp) {
                const int dy = stp / 3, dx = stp % 3;   // const-folded
                int sl = rbase + wave + dy; if (sl >= RING) sl -= RING;
                const int xp = xm + pix + dx;
                const int pos = quad ^ ((xp >> 1) & 3); // same involution
                bf16x8 a = *(const bf16x8*)&sx[sl][xp][pos * 8];
                acc0 = __builtin_amdgcn_mfma_f32_16x16x32_bf16(a, bw[stp][0], acc0, 0, 0, 0);
                acc1 = __builtin_amdgcn_mfma_f32_16x16x32_bf16(a, bw[stp][1], acc1, 0, 0, 0);
            }
            // D: m = quad*4 + reg (pixel), n = pix (o)
            const int base0 = ((n*O + pix     ) * H + gy_out) * W + x0 + xm + quad*4;
            const int base1 = ((n*O + 16 + pix) * H + gy_out) * W + x0 + xm + quad*4;
            f32x4 o0 = acc0 + b0;
            f32x4 o1 = acc1 + b1;
            *(f32x4*)(out + base0) = o0;
            *(f32x4*)(out + base1) = o1;
        }

        // ---- pack + ds_write staged rows into ring slots rbase+6..rbase+9 ----
        // (disjoint from read window rbase..rbase+5 mod 12; prior readers of
        // these slots passed the previous barrier)
        if (s + 1 < NS) {
            #pragma unroll
            for (int k = 0; k < 4; ++k) {
                int sl = rbase + 6 + k; if (sl >= RING) sl -= RING;
                int gxl = lane + 1;
                int pos = wave ^ ((gxl >> 1) & 3);
                *(uint4*)&sx[sl][gxl][pos * 8] = pack8(v[k]);
            }
            if (tid < 32) {
                int sl = rbase + 6 + hrow; if (sl >= RING) sl -= RING;
                int pos = hciq ^ ((hcol >> 1) & 3);
                *(uint4*)&sx[sl][hcol][pos * 8] = pack8(vh);
            }
            __syncthreads();
        }
    }
}

extern "C" void kernel_launch(void* const* d_in, const int* in_sizes, int n_in,
                              void* d_out, int out_size, void* d_ws, size_t ws_size,
                              hipStream_t stream) {
    const float* x    = (const float*)d_in[0];
    const float* k0   = (const float*)d_in[1];
    const float* k1   = (const float*)d_in[2];
    const float* k2   = (const float*)d_in[3];
    const float* k3   = (const float*)d_in[4];
    const float* bias = (const float*)d_in[5];
    float* out = (float*)d_out;
    unsigned short* wbuf = (unsigned short*)d_ws;  // 9216 bf16 = 18 KB

    recon_w<<<36, 256, 0, stream>>>(k0, k1, k2, k3, wbuf);
    // 8 images * (512/SH=32) * (512/TW=8) = 2048 blocks
    conv_mfma<<<2048, 256, 0, stream>>>(x, wbuf, bias, out);
}